// Round 16
// baseline (863.502 us; speedup 1.0000x reference)
//
#include <hip/hip_runtime.h>
#include <math.h>
#include <stdint.h>

#define BB 2
#define LL 1024
#define DM 768
#define NL 2
#define VV 50264
#define VPAD 50304   // 393 * 128
#define DS 16
#define DI 1536
#define DR 48
#define DC 4
#define MM (BB*LL)

#define CH 32
#define NC (LL/CH)   // 32
#define CONVL 16

#define KS 8         // xproj K-split

typedef __attribute__((ext_vector_type(8))) short short8;
typedef __attribute__((ext_vector_type(4))) float f32x4;

#define AS3(p) ((__attribute__((address_space(3))) unsigned int*)(unsigned int)(uintptr_t)(p))
#define AS1(p) ((const __attribute__((address_space(1))) unsigned int*)(uintptr_t)(p))

__device__ __forceinline__ unsigned short f2bf(float v) {
    union { float f; unsigned u; } x; x.f = v;
    unsigned r = x.u + 0x7fffu + ((x.u >> 16) & 1u);
    return (unsigned short)(r >> 16);
}
__device__ __forceinline__ float bf2f(unsigned short h) {
    union { unsigned u; float f; } x; x.u = (unsigned)h << 16;
    return x.f;
}

// ---------------- embedding gather (f32 + bf16) ----------------
__global__ __launch_bounds__(256) void embed_kernel(
    const int* __restrict__ ids, const float* __restrict__ emb,
    float* __restrict__ x, unsigned short* __restrict__ x16)
{
    int m = blockIdx.x;
    int v = ids[m];
    const float* src = emb + (size_t)v * DM;
    float* dst = x + (size_t)m * DM;
    unsigned short* dst16 = x16 + (size_t)m * DM;
    for (int i = threadIdx.x; i < DM; i += 256) {
        float f = src[i];
        dst[i] = f;
        dst16[i] = f2bf(f);
    }
}

// ---------------- emb f32 [VV][DM] -> bf16 [VPAD][DM] (pad rows = 0) ----------------
__global__ __launch_bounds__(256) void emb_convert_kernel(
    const float* __restrict__ emb, unsigned short* __restrict__ out)
{
    size_t i8 = (size_t)blockIdx.x * 256 + threadIdx.x;
    size_t row = i8 / 96;
    size_t col8 = (i8 - row * 96) * 8;
    if (row >= VPAD) return;
    ushort4 o0, o1;
    if (row < VV) {
        const float* p = emb + row * DM + col8;
        float4 v0 = *(const float4*)p;
        float4 v1 = *(const float4*)(p + 4);
        o0.x = f2bf(v0.x); o0.y = f2bf(v0.y); o0.z = f2bf(v0.z); o0.w = f2bf(v0.w);
        o1.x = f2bf(v1.x); o1.y = f2bf(v1.y); o1.z = f2bf(v1.z); o1.w = f2bf(v1.w);
    } else {
        o0 = make_ushort4(0, 0, 0, 0);
        o1 = o0;
    }
    unsigned short* op = out + row * DM + col8;
    *(ushort4*)op = o0;
    *(ushort4*)(op + 4) = o1;
}

// ---------------- transpose+convert: in [L][R][C] f32 -> out [L][C][R] bf16 ----------------
__global__ __launch_bounds__(256) void transpose_bf16_kernel(
    const float* __restrict__ in, unsigned short* __restrict__ out, int R, int C)
{
    __shared__ float t[32][33];
    int l = blockIdx.z;
    int r0 = blockIdx.y * 32, c0 = blockIdx.x * 32;
    int tx = threadIdx.x & 31, ty = threadIdx.x >> 5;
    const float* ip = in + (size_t)l * R * C;
    unsigned short* op = out + (size_t)l * C * R;
    #pragma unroll
    for (int j = 0; j < 32; j += 8)
        t[ty + j][tx] = ip[(size_t)(r0 + ty + j) * C + c0 + tx];
    __syncthreads();
    #pragma unroll
    for (int j = 0; j < 32; j += 8)
        op[(size_t)(c0 + ty + j) * R + r0 + tx] = f2bf(t[tx][ty + j]);
}

// ---------------- xproj_w [L][DI][80] f32 -> [L][128][DI] bf16 (rows >=80 zero) ----------------
__global__ __launch_bounds__(256) void xprojw_convert_kernel(
    const float* __restrict__ in, unsigned short* __restrict__ out)
{
    __shared__ float t[32][33];
    int l = blockIdx.z;
    int r0 = blockIdx.y * 32;        // source row tile (DI)
    int c0 = blockIdx.x * 32;        // source col tile (0..127)
    int tx = threadIdx.x & 31, ty = threadIdx.x >> 5;
    const float* ip = in + (size_t)l * DI * 80;
    unsigned short* op = out + (size_t)l * 128 * DI;
    #pragma unroll
    for (int j = 0; j < 32; j += 8) {
        int c = c0 + tx;
        t[ty + j][tx] = (c < 80) ? ip[(size_t)(r0 + ty + j) * 80 + c] : 0.f;
    }
    __syncthreads();
    #pragma unroll
    for (int j = 0; j < 32; j += 8)
        op[(size_t)(c0 + ty + j) * DI + r0 + tx] = f2bf(t[tx][ty + j]);
}

// ---------------- dt_w [L][48][1536] f32 -> [L][1536][64] bf16 (cols >=48 zero) ----------------
__global__ __launch_bounds__(256) void dtw_convert_kernel(
    const float* __restrict__ in, unsigned short* __restrict__ out)
{
    __shared__ float t[32][33];
    int l = blockIdx.z;
    int r0 = blockIdx.y * 32;        // source row tile (0..63 padded k)
    int c0 = blockIdx.x * 32;        // source col tile (1536 n)
    int tx = threadIdx.x & 31, ty = threadIdx.x >> 5;
    const float* ip = in + (size_t)l * DR * DI;
    unsigned short* op = out + (size_t)l * DI * 64;
    #pragma unroll
    for (int j = 0; j < 32; j += 8) {
        int r = r0 + ty + j;
        t[ty + j][tx] = (r < DR) ? ip[(size_t)r * DI + c0 + tx] : 0.f;
    }
    __syncthreads();
    #pragma unroll
    for (int j = 0; j < 32; j += 8)
        op[(size_t)(c0 + ty + j) * 64 + r0 + tx] = f2bf(t[tx][ty + j]);
}

// ---------------- 128x128 MFMA GEMM (in-proj), bf16 output ----------------
__global__ __launch_bounds__(256) void gemm_mfma_bt(
    const unsigned short* __restrict__ A, const unsigned short* __restrict__ B,
    const float* __restrict__ bias, unsigned short* __restrict__ C16,
    int M, int N, int K, int MT, int NTILES)
{
    int T = MT * NTILES;
    int q = T >> 3, r = T & 7;
    int orig = blockIdx.x;
    int xcd = orig & 7, u = orig >> 3;
    int wg = (xcd < r ? xcd * (q + 1) : r * (q + 1) + (xcd - r) * q) + u;
    int mt = wg % MT, nt = wg / MT;

    __shared__ unsigned short As[3][128 * 32];
    __shared__ unsigned short Bs[3][128 * 32];
    int tid = threadIdx.x;
    int w = tid >> 6, lane = tid & 63;
    int m0 = mt * 128, n0 = nt * 128;

    int rA = lane >> 2;
    int kb = (lane & 3) * 8;
    const unsigned short* gA0 = A + (size_t)(m0 + w * 16 + rA) * K + kb;
    const unsigned short* gA1 = gA0 + (size_t)64 * K;
    const unsigned short* gB0 = B + (size_t)(n0 + w * 16 + rA) * K + kb;
    const unsigned short* gB1 = gB0 + (size_t)64 * K;

    int lr = lane & 15, lk = lane >> 4;
    int wr = (w >> 1) * 64, wc = (w & 1) * 64;

    f32x4 acc[4][4] = {};

#define STAGE(k0, buf) do { \
    __builtin_amdgcn_global_load_lds(AS1(gA0 + (k0)), AS3(&As[buf][(w * 16) * 32]), 16, 0, 0); \
    __builtin_amdgcn_global_load_lds(AS1(gA1 + (k0)), AS3(&As[buf][(64 + w * 16) * 32]), 16, 0, 0); \
    __builtin_amdgcn_global_load_lds(AS1(gB0 + (k0)), AS3(&Bs[buf][(w * 16) * 32]), 16, 0, 0); \
    __builtin_amdgcn_global_load_lds(AS1(gB1 + (k0)), AS3(&Bs[buf][(64 + w * 16) * 32]), 16, 0, 0); \
} while (0)

#define COMPUTE(buf) do { \
    short8 a[4], b[4]; \
    _Pragma("unroll") \
    for (int f = 0; f < 4; ++f) \
        a[f] = *(const short8*)&As[buf][(wr + f * 16 + lr) * 32 + lk * 8]; \
    _Pragma("unroll") \
    for (int f = 0; f < 4; ++f) \
        b[f] = *(const short8*)&Bs[buf][(wc + f * 16 + lr) * 32 + lk * 8]; \
    _Pragma("unroll") \
    for (int i = 0; i < 4; ++i) \
        _Pragma("unroll") \
        for (int j = 0; j < 4; ++j) \
            acc[i][j] = __builtin_amdgcn_mfma_f32_16x16x32_bf16(a[i], b[j], acc[i][j], 0, 0, 0); \
} while (0)

    int nsteps = K / 32;
    STAGE(0, 0);
    STAGE(32, 1);
    asm volatile("s_waitcnt vmcnt(4)" ::: "memory");
    __builtin_amdgcn_s_barrier();
    __builtin_amdgcn_sched_barrier(0);

    for (int t = 0; t < nsteps; ++t) {
        int cur = t % 3;
        if (t + 2 < nsteps)
            STAGE((t + 2) * 32, (t + 2) % 3);
        COMPUTE(cur);
        if (t + 1 < nsteps) {
            if (t + 2 < nsteps)
                asm volatile("s_waitcnt vmcnt(4)" ::: "memory");
            else
                asm volatile("s_waitcnt vmcnt(0)" ::: "memory");
            __builtin_amdgcn_s_barrier();
            __builtin_amdgcn_sched_barrier(0);
        }
    }

#undef STAGE
#undef COMPUTE

    #pragma unroll
    for (int i = 0; i < 4; ++i) {
        int row = m0 + wr + i * 16 + lk * 4;
        #pragma unroll
        for (int j = 0; j < 4; ++j) {
            int col = n0 + wc + j * 16 + lr;
            if (col < N) {
                float bv = bias ? bias[col] : 0.f;
                #pragma unroll
                for (int r2 = 0; r2 < 4; ++r2) {
                    float v = acc[i][j][r2] + bv;
                    C16[(size_t)(row + r2) * N + col] = f2bf(v);
                }
            }
        }
    }
}

// ---------------- out-proj K-split partial GEMM ----------------
__global__ __launch_bounds__(256) void gemm_out_part(
    const unsigned short* __restrict__ A, const unsigned short* __restrict__ B,
    float* __restrict__ part)
{
    const int T = 16 * 6 * 2;
    int q = T >> 3;
    int orig = blockIdx.x;
    int xcd = orig & 7, u = orig >> 3;
    int wg = xcd * q + u;
    int mt = wg % 16;
    int rest = wg / 16;
    int nt = rest % 6, z = rest / 6;

    __shared__ unsigned short As[3][128 * 32];
    __shared__ unsigned short Bs[3][128 * 32];
    int tid = threadIdx.x;
    int w = tid >> 6, lane = tid & 63;
    int m0 = mt * 128, n0 = nt * 128;
    int kh = z * 768;

    int rA = lane >> 2;
    int kb = (lane & 3) * 8;
    const unsigned short* gA0 = A + (size_t)(m0 + w * 16 + rA) * DI + kh + kb;
    const unsigned short* gA1 = gA0 + (size_t)64 * DI;
    const unsigned short* gB0 = B + (size_t)(n0 + w * 16 + rA) * DI + kh + kb;
    const unsigned short* gB1 = gB0 + (size_t)64 * DI;

    int lr = lane & 15, lk = lane >> 4;
    int wr = (w >> 1) * 64, wc = (w & 1) * 64;

    f32x4 acc[4][4] = {};

#define STAGE(k0, buf) do { \
    __builtin_amdgcn_global_load_lds(AS1(gA0 + (k0)), AS3(&As[buf][(w * 16) * 32]), 16, 0, 0); \
    __builtin_amdgcn_global_load_lds(AS1(gA1 + (k0)), AS3(&As[buf][(64 + w * 16) * 32]), 16, 0, 0); \
    __builtin_amdgcn_global_load_lds(AS1(gB0 + (k0)), AS3(&Bs[buf][(w * 16) * 32]), 16, 0, 0); \
    __builtin_amdgcn_global_load_lds(AS1(gB1 + (k0)), AS3(&Bs[buf][(64 + w * 16) * 32]), 16, 0, 0); \
} while (0)

#define COMPUTE(buf) do { \
    short8 a[4], b[4]; \
    _Pragma("unroll") \
    for (int f = 0; f < 4; ++f) \
        a[f] = *(const short8*)&As[buf][(wr + f * 16 + lr) * 32 + lk * 8]; \
    _Pragma("unroll") \
    for (int f = 0; f < 4; ++f) \
        b[f] = *(const short8*)&Bs[buf][(wc + f * 16 + lr) * 32 + lk * 8]; \
    _Pragma("unroll") \
    for (int i = 0; i < 4; ++i) \
        _Pragma("unroll") \
        for (int j = 0; j < 4; ++j) \
            acc[i][j] = __builtin_amdgcn_mfma_f32_16x16x32_bf16(a[i], b[j], acc[i][j], 0, 0, 0); \
} while (0)

    const int nsteps = 768 / 32;   // 24
    STAGE(0, 0);
    STAGE(32, 1);
    asm volatile("s_waitcnt vmcnt(4)" ::: "memory");
    __builtin_amdgcn_s_barrier();
    __builtin_amdgcn_sched_barrier(0);

    for (int t = 0; t < nsteps; ++t) {
        int cur = t % 3;
        if (t + 2 < nsteps)
            STAGE((t + 2) * 32, (t + 2) % 3);
        COMPUTE(cur);
        if (t + 1 < nsteps) {
            if (t + 2 < nsteps)
                asm volatile("s_waitcnt vmcnt(4)" ::: "memory");
            else
                asm volatile("s_waitcnt vmcnt(0)" ::: "memory");
            __builtin_amdgcn_s_barrier();
            __builtin_amdgcn_sched_barrier(0);
        }
    }

#undef STAGE
#undef COMPUTE

    float* op = part + (size_t)z * MM * DM;
    #pragma unroll
    for (int i = 0; i < 4; ++i) {
        int row = m0 + wr + i * 16 + lk * 4;
        #pragma unroll
        for (int j = 0; j < 4; ++j) {
            int col = n0 + wc + j * 16 + lr;
            #pragma unroll
            for (int r2 = 0; r2 < 4; ++r2)
                op[(size_t)(row + r2) * DM + col] = acc[i][j][r2];
        }
    }
}

// ---------------- xproj MFMA partial: part[z] = u @ xprojT^T over K-range z ----------------
// grid 128 blocks: mt = b % 16, z = b / 16. B = xprojT [128][DI] (rows>=80 zero).
__global__ __launch_bounds__(256) void xproj_mfma_part(
    const unsigned short* __restrict__ A, const unsigned short* __restrict__ B,
    float* __restrict__ part)
{
    int mt = blockIdx.x % 16;
    int z  = blockIdx.x / 16;

    __shared__ unsigned short As[3][128 * 32];
    __shared__ unsigned short Bs[3][128 * 32];
    int tid = threadIdx.x;
    int w = tid >> 6, lane = tid & 63;
    int m0 = mt * 128;
    int kh = z * (DI / KS);   // 192

    int rA = lane >> 2;
    int kb = (lane & 3) * 8;
    const unsigned short* gA0 = A + (size_t)(m0 + w * 16 + rA) * DI + kh + kb;
    const unsigned short* gA1 = gA0 + (size_t)64 * DI;
    const unsigned short* gB0 = B + (size_t)(w * 16 + rA) * DI + kh + kb;
    const unsigned short* gB1 = gB0 + (size_t)64 * DI;

    int lr = lane & 15, lk = lane >> 4;
    int wr = (w >> 1) * 64, wc = (w & 1) * 64;

    f32x4 acc[4][4] = {};

#define STAGE(k0, buf) do { \
    __builtin_amdgcn_global_load_lds(AS1(gA0 + (k0)), AS3(&As[buf][(w * 16) * 32]), 16, 0, 0); \
    __builtin_amdgcn_global_load_lds(AS1(gA1 + (k0)), AS3(&As[buf][(64 + w * 16) * 32]), 16, 0, 0); \
    __builtin_amdgcn_global_load_lds(AS1(gB0 + (k0)), AS3(&Bs[buf][(w * 16) * 32]), 16, 0, 0); \
    __builtin_amdgcn_global_load_lds(AS1(gB1 + (k0)), AS3(&Bs[buf][(64 + w * 16) * 32]), 16, 0, 0); \
} while (0)

#define COMPUTE(buf) do { \
    short8 a[4], b[4]; \
    _Pragma("unroll") \
    for (int f = 0; f < 4; ++f) \
        a[f] = *(const short8*)&As[buf][(wr + f * 16 + lr) * 32 + lk * 8]; \
    _Pragma("unroll") \
    for (int f = 0; f < 4; ++f) \
        b[f] = *(const short8*)&Bs[buf][(wc + f * 16 + lr) * 32 + lk * 8]; \
    _Pragma("unroll") \
    for (int i = 0; i < 4; ++i) \
        _Pragma("unroll") \
        for (int j = 0; j < 4; ++j) \
            acc[i][j] = __builtin_amdgcn_mfma_f32_16x16x32_bf16(a[i], b[j], acc[i][j], 0, 0, 0); \
} while (0)

    const int nsteps = (DI / KS) / 32;   // 6
    STAGE(0, 0);
    STAGE(32, 1);
    asm volatile("s_waitcnt vmcnt(4)" ::: "memory");
    __builtin_amdgcn_s_barrier();
    __builtin_amdgcn_sched_barrier(0);

    for (int t = 0; t < nsteps; ++t) {
        int cur = t % 3;
        if (t + 2 < nsteps)
            STAGE((t + 2) * 32, (t + 2) % 3);
        COMPUTE(cur);
        if (t + 1 < nsteps) {
            if (t + 2 < nsteps)
                asm volatile("s_waitcnt vmcnt(4)" ::: "memory");
            else
                asm volatile("s_waitcnt vmcnt(0)" ::: "memory");
            __builtin_amdgcn_s_barrier();
            __builtin_amdgcn_sched_barrier(0);
        }
    }

#undef STAGE
#undef COMPUTE

    float* op = part + (size_t)z * MM * 80;
    #pragma unroll
    for (int i = 0; i < 4; ++i) {
        int row = m0 + wr + i * 16 + lk * 4;
        #pragma unroll
        for (int j = 0; j < 4; ++j) {
            int col = wc + j * 16 + lr;
            if (col < 80) {
                #pragma unroll
                for (int r2 = 0; r2 < 4; ++r2)
                    op[(size_t)(row + r2) * 80 + col] = acc[i][j][r2];
            }
        }
    }
}

// ---------------- xproj reduce: dbc f32 + dbc48 bf16 (cols<48; 48..63 zero) ----------------
__global__ __launch_bounds__(256) void xproj_reduce_kernel(
    const float* __restrict__ part, float* __restrict__ dbc,
    unsigned short* __restrict__ dbc48)
{
    int i = blockIdx.x * 256 + threadIdx.x;
    if (i >= MM * 80) return;
    float s = 0.f;
    #pragma unroll
    for (int z = 0; z < KS; ++z) s += part[(size_t)z * MM * 80 + i];
    dbc[i] = s;
    int m = i / 80, col = i - m * 80;
    if (col < DR) dbc48[(size_t)m * 64 + col] = f2bf(s);
    else if (col < 64) dbc48[(size_t)m * 64 + col] = 0;
}

// ---------------- dt MFMA: delta = bf16(softplus(dbc48 @ dtwT^T + dt_b)) ----------------
// A [2048][64] bf16, B [1536][64] bf16, K=64 (2 steps). grid 192: mt=b%16, nt=b/16.
__global__ __launch_bounds__(256) void dt_mfma(
    const unsigned short* __restrict__ A, const unsigned short* __restrict__ B,
    const float* __restrict__ bias, unsigned short* __restrict__ C16)
{
    int mt = blockIdx.x % 16;
    int nt = blockIdx.x / 16;

    __shared__ unsigned short As[2][128 * 32];
    __shared__ unsigned short Bs[2][128 * 32];
    int tid = threadIdx.x;
    int w = tid >> 6, lane = tid & 63;
    int m0 = mt * 128, n0 = nt * 128;

    int rA = lane >> 2;
    int kb = (lane & 3) * 8;
    const unsigned short* gA0 = A + (size_t)(m0 + w * 16 + rA) * 64 + kb;
    const unsigned short* gA1 = gA0 + (size_t)64 * 64;
    const unsigned short* gB0 = B + (size_t)(n0 + w * 16 + rA) * 64 + kb;
    const unsigned short* gB1 = gB0 + (size_t)64 * 64;

    int lr = lane & 15, lk = lane >> 4;
    int wr = (w >> 1) * 64, wc = (w & 1) * 64;

    f32x4 acc[4][4] = {};

#define STAGE(k0, buf) do { \
    __builtin_amdgcn_global_load_lds(AS1(gA0 + (k0)), AS3(&As[buf][(w * 16) * 32]), 16, 0, 0); \
    __builtin_amdgcn_global_load_lds(AS1(gA1 + (k0)), AS3(&As[buf][(64 + w * 16) * 32]), 16, 0, 0); \
    __builtin_amdgcn_global_load_lds(AS1(gB0 + (k0)), AS3(&Bs[buf][(w * 16) * 32]), 16, 0, 0); \
    __builtin_amdgcn_global_load_lds(AS1(gB1 + (k0)), AS3(&Bs[buf][(64 + w * 16) * 32]), 16, 0, 0); \
} while (0)

#define COMPUTE(buf) do { \
    short8 a[4], b[4]; \
    _Pragma("unroll") \
    for (int f = 0; f < 4; ++f) \
        a[f] = *(const short8*)&As[buf][(wr + f * 16 + lr) * 32 + lk * 8]; \
    _Pragma("unroll") \
    for (int f = 0; f < 4; ++f) \
        b[f] = *(const short8*)&Bs[buf][(wc + f * 16 + lr) * 32 + lk * 8]; \
    _Pragma("unroll") \
    for (int i = 0; i < 4; ++i) \
        _Pragma("unroll") \
        for (int j = 0; j < 4; ++j) \
            acc[i][j] = __builtin_amdgcn_mfma_f32_16x16x32_bf16(a[i], b[j], acc[i][j], 0, 0, 0); \
} while (0)

    STAGE(0, 0);
    STAGE(32, 1);
    asm volatile("s_waitcnt vmcnt(4)" ::: "memory");
    __builtin_amdgcn_s_barrier();
    __builtin_amdgcn_sched_barrier(0);
    COMPUTE(0);
    asm volatile("s_waitcnt vmcnt(0)" ::: "memory");
    __builtin_amdgcn_s_barrier();
    __builtin_amdgcn_sched_barrier(0);
    COMPUTE(1);

#undef STAGE
#undef COMPUTE

    #pragma unroll
    for (int i = 0; i < 4; ++i) {
        int row = m0 + wr + i * 16 + lk * 4;
        #pragma unroll
        for (int j = 0; j < 4; ++j) {
            int col = n0 + wc + j * 16 + lr;
            float bv = bias[col];
            #pragma unroll
            for (int r2 = 0; r2 < 4; ++r2) {
                float v = acc[i][j][r2] + bv;
                v = fmaxf(v, 0.f) + log1pf(expf(-fabsf(v)));
                C16[(size_t)(row + r2) * DI + col] = f2bf(v);
            }
        }
    }
}

// ---------------- 256x128 phase-split MFMA GEMM (logits) ----------------
__global__ __launch_bounds__(512) void gemm_logits(
    const unsigned short* __restrict__ A, const unsigned short* __restrict__ B,
    float* __restrict__ C, int M, int N, int K, int MT, int NTILES)
{
    int T = MT * NTILES;
    int q = T >> 3, r = T & 7;
    int orig = blockIdx.x;
    int xcd = orig & 7, u = orig >> 3;
    int wg = (xcd < r ? xcd * (q + 1) : r * (q + 1) + (xcd - r) * q) + u;
    int mt = wg % MT, nt = wg / MT;

    __shared__ unsigned short As[3][256 * 32];
    __shared__ unsigned short Bs[3][128 * 32];
    int tid = threadIdx.x;
    int w = tid >> 6, lane = tid & 63;
    int wm = w >> 1, wn = w & 1;
    int m0 = mt * 256, n0 = nt * 128;

    int srow = tid >> 2;
    int schunk = (tid & 3) ^ ((srow & 3) ^ ((srow >> 2) & 3));
    const unsigned short* gA0 = A + (size_t)(m0 + srow) * K + schunk * 8;
    const unsigned short* gA1 = gA0 + (size_t)128 * K;
    const unsigned short* gB0 = B + (size_t)(n0 + srow) * K + schunk * 8;

    int lr = lane & 15, lk = lane >> 4;
    int rc = (lk ^ ((lr & 3) ^ ((lr >> 2) & 3))) * 8;

    f32x4 acc[4][4] = {};

#define STAGE_A(k0, buf) do { \
    __builtin_amdgcn_global_load_lds(AS1(gA0 + (k0)), AS3(&As[buf][(w * 16) * 32]), 16, 0, 0); \
    __builtin_amdgcn_global_load_lds(AS1(gA1 + (k0)), AS3(&As[buf][(128 + w * 16) * 32]), 16, 0, 0); \
} while (0)
#define STAGE_B(k0, buf) do { \
    __builtin_amdgcn_global_load_lds(AS1(gB0 + (k0)), AS3(&Bs[buf][(w * 16) * 32]), 16, 0, 0); \
} while (0)

    int nsteps = K / 32;

    STAGE_A(0, 0); STAGE_B(0, 0);
    STAGE_A(32, 1); STAGE_B(32, 1);
    asm volatile("s_waitcnt vmcnt(3)" ::: "memory");
    __builtin_amdgcn_s_barrier();
    __builtin_amdgcn_sched_barrier(0);

    for (int t = 0; t < nsteps; ++t) {
        int s = t % 3;
        int sn = (t + 2) % 3;
        bool stage2 = (t + 2) < nsteps;
        short8 av[2], bv[4];

        #pragma unroll
        for (int f = 0; f < 2; ++f)
            av[f] = *(const short8*)&As[s][(wm * 64 + f * 16 + lr) * 32 + rc];
        #pragma unroll
        for (int f = 0; f < 4; ++f)
            bv[f] = *(const short8*)&Bs[s][(wn * 64 + f * 16 + lr) * 32 + rc];
        if (stage2) STAGE_A((t + 2) * 32, sn);
        __builtin_amdgcn_s_barrier();
        asm volatile("s_waitcnt lgkmcnt(0)" ::: "memory");
        __builtin_amdgcn_sched_barrier(0);
        __builtin_amdgcn_s_setprio(1);
        #pragma unroll
        for (int i = 0; i < 2; ++i)
            #pragma unroll
            for (int j = 0; j < 4; ++j)
                acc[i][j] = __builtin_amdgcn_mfma_f32_16x16x32_bf16(av[i], bv[j], acc[i][j], 0, 0, 0);
        __builtin_amdgcn_s_setprio(0);
        __builtin_amdgcn_s_barrier();

        #pragma unroll
        for (int f = 0; f < 2; ++f)
            av[f] = *(const short8*)&As[s][(wm * 64 + (2 + f) * 16 + lr) * 32 + rc];
        if (stage2) STAGE_B((t + 2) * 32, sn);
        __builtin_amdgcn_s_barrier();
        asm volatile("s_waitcnt lgkmcnt(0)" ::: "memory");
        __builtin_amdgcn_sched_barrier(0);
        __builtin_amdgcn_s_setprio(1);
        #pragma unroll
        for (int i = 0; i < 2; ++i)
            #pragma unroll
            for (int j = 0; j < 4; ++j)
                acc[2 + i][j] = __builtin_amdgcn_mfma_f32_16x16x32_bf16(av[i], bv[j], acc[2 + i][j], 0, 0, 0);
        __builtin_amdgcn_s_setprio(0);

        if (t + 1 < nsteps) {
            if (stage2)
                asm volatile("s_waitcnt vmcnt(3)" ::: "memory");
            else
                asm volatile("s_waitcnt vmcnt(0)" ::: "memory");
            __builtin_amdgcn_s_barrier();
            __builtin_amdgcn_sched_barrier(0);
        }
    }

#undef STAGE_A
#undef STAGE_B

    #pragma unroll
    for (int i = 0; i < 4; ++i) {
        int row = m0 + wm * 64 + i * 16 + lk * 4;
        #pragma unroll
        for (int j = 0; j < 4; ++j) {
            int col = n0 + wn * 64 + j * 16 + lr;
            if (col < N) {
                #pragma unroll
                for (int r2 = 0; r2 < 4; ++r2)
                    C[(size_t)(row + r2) * N + col] = acc[i][j][r2];
            }
        }
    }
}

// ---------------- causal depthwise conv1d + SiLU (bf16 in/out) ----------------
__global__ __launch_bounds__(256) void conv_silu_kernel(
    const unsigned short* __restrict__ xr, const float* __restrict__ cw,
    const float* __restrict__ cb, unsigned short* __restrict__ u)
{
    int d = blockIdx.x * 256 + threadIdx.x;
    int l0 = blockIdx.y * CONVL;
    int b = blockIdx.z;
    const float4 wv = *(const float4*)(cw + (size_t)d * DC);
    float bias = cb[d];
    const unsigned short* xp = xr + ((size_t)(b * LL + l0)) * (2 * DI) + d;
    unsigned short* up = u + ((size_t)(b * LL + l0)) * DI + d;
    const ptrdiff_t RS = 2 * DI;
    float xm3 = (l0 >= 3) ? bf2f(xp[-3 * RS]) : 0.f;
    float xm2 = (l0 >= 2) ? bf2f(xp[-2 * RS]) : 0.f;
    float xm1 = (l0 >= 1) ? bf2f(xp[-1 * RS]) : 0.f;
    #pragma unroll
    for (int l = 0; l < CONVL; ++l) {
        float xc = bf2f(xp[(ptrdiff_t)l * RS]);
        float acc = bias;
        acc = fmaf(wv.x, xm3, acc);
        acc = fmaf(wv.y, xm2, acc);
        acc = fmaf(wv.z, xm1, acc);
        acc = fmaf(wv.w, xc, acc);
        float s = acc / (1.f + expf(-acc));
        up[(size_t)l * DI] = f2bf(s);
        xm3 = xm2; xm2 = xm1; xm1 = xc;
    }
}

// ---------------- chunked selective scan, lane-per-d layout ----------------
__global__ __launch_bounds__(256) void scan_reduce_kernel(
    const unsigned short* __restrict__ delta, const unsigned short* __restrict__ u,
    const float* __restrict__ dbc, const float* __restrict__ A_log,
    float* __restrict__ P, float* __restrict__ Q)
{
    int d = blockIdx.x * 256 + threadIdx.x;
    int c = blockIdx.y;
    int b = blockIdx.z;

    float Av[DS], invA[DS];
    {
        const float4* ap = (const float4*)(A_log + (size_t)d * DS);
        #pragma unroll
        for (int n4 = 0; n4 < 4; ++n4) {
            float4 a = ap[n4];
            Av[n4 * 4 + 0] = -expf(a.x); Av[n4 * 4 + 1] = -expf(a.y);
            Av[n4 * 4 + 2] = -expf(a.z); Av[n4 * 4 + 3] = -expf(a.w);
        }
        #pragma unroll
        for (int n = 0; n < DS; ++n) invA[n] = 1.f / (Av[n] + 1e-7f);
    }

    float p[DS], s[DS];
    #pragma unroll
    for (int n = 0; n < DS; ++n) { p[n] = 1.f; s[n] = 0.f; }

    const unsigned short* dp = delta + ((size_t)b * LL + c * CH) * DI + d;
    const unsigned short* up = u     + ((size_t)b * LL + c * CH) * DI + d;
    const float* bb = dbc + ((size_t)b * LL + c * CH) * 80 + DR;

    for (int l = 0; l < CH; ++l) {
        float dlt = bf2f(dp[(size_t)l * DI]);
        float uv  = bf2f(up[(size_t)l * DI]);
        float Bv[DS];
        {
            const float4* bp4 = (const float4*)(bb + (size_t)l * 80);
            #pragma unroll
            for (int n4 = 0; n4 < 4; ++n4) {
                float4 v = bp4[n4];
                Bv[n4 * 4 + 0] = v.x; Bv[n4 * 4 + 1] = v.y;
                Bv[n4 * 4 + 2] = v.z; Bv[n4 * 4 + 3] = v.w;
            }
        }
        #pragma unroll
        for (int n = 0; n < DS; ++n) {
            float dA = expf(dlt * Av[n]);
            float dBu = (dA - 1.f) * invA[n] * Bv[n] * uv;
            p[n] *= dA;
            s[n] = fmaf(dA, s[n], dBu);
        }
    }

    float* Pp = P + (((size_t)b * NC + c) * DI + d) * DS;
    float* Qp = Q + (((size_t)b * NC + c) * DI + d) * DS;
    #pragma unroll
    for (int n4 = 0; n4 < 4; ++n4) {
        ((float4*)Pp)[n4] = make_float4(p[n4 * 4 + 0], p[n4 * 4 + 1], p[n4 * 4 + 2], p[n4 * 4 + 3]);
        ((float4*)Qp)[n4] = make_float4(s[n4 * 4 + 0], s[n4 * 4 + 1], s[n4 * 4 + 2], s[n4 * 4 + 3]);
    }
}

__global__ __launch_bounds__(256) void scan_combine_kernel(
    const float* __restrict__ P, const float* __restrict__ Q, float* __restrict__ Sinit)
{
    int t = blockIdx.x * 256 + threadIdx.x;
    int b = t / (DI * DS);
    int dn = t - b * (DI * DS);
    float s = 0.f;
    for (int c = 0; c < NC; ++c) {
        size_t idx = ((size_t)b * NC + c) * (DI * DS) + dn;
        Sinit[idx] = s;
        s = fmaf(P[idx], s, Q[idx]);
    }
}

__global__ __launch_bounds__(256) void scan_apply_kernel(
    const unsigned short* __restrict__ delta, const unsigned short* __restrict__ u,
    const float* __restrict__ dbc, const unsigned short* __restrict__ xr,
    const float* __restrict__ A_log, const float* __restrict__ Dp,
    const float* __restrict__ Sinit, unsigned short* __restrict__ y16)
{
    int d = blockIdx.x * 256 + threadIdx.x;
    int c = blockIdx.y;
    int b = blockIdx.z;

    float Av[DS], invA[DS];
    {
        const float4* ap = (const float4*)(A_log + (size_t)d * DS);
        #pragma unroll
        for (int n4 = 0; n4 < 4; ++n4) {
            float4 a = ap[n4];
            Av[n4 * 4 + 0] = -expf(a.x); Av[n4 * 4 + 1] = -expf(a.y);
            Av[n4 * 4 + 2] = -expf(a.z); Av[n4 * 4 + 3] = -expf(a.w);
        }
        #pragma unroll
        for (int n = 0; n < DS; ++n) invA[n] = 1.f / (Av[n] + 1e-7f);
    }
    float Dv = Dp[d];

    float s[DS];
    {
        const float4* Sp = (const float4*)(Sinit + (((size_t)b * NC + c) * DI + d) * DS);
        #pragma unroll
        for (int n4 = 0; n4 < 4; ++n4) {
            float4 sw = Sp[n4];
            s[n4 * 4 + 0] = sw.x; s[n4 * 4 + 1] = sw.y;
            s[n4 * 4 + 2] = sw.z; s[n4 * 4 + 3] = sw.w;
        }
    }

    const unsigned short* dp = delta + ((size_t)b * LL + c * CH) * DI + d;
    const unsigned short* up = u     + ((size_t)b * LL + c * CH) * DI + d;
    const unsigned short* xp = xr    + ((size_t)b * LL + c * CH) * (2 * DI) + DI + d;
    const float* bb = dbc + ((size_t)b * LL + c * CH) * 80 + DR;
    unsigned short* yp = y16 + ((size_t)b * LL + c * CH) * DI + d;

    for (int l = 0; l < CH; ++l) {
        float dlt = bf2f(dp[(size_t)l * DI]);
        float uv  = bf2f(up[(size_t)l * DI]);
        float rv  = bf2f(xp[(size_t)l * (2 * DI)]);
        float Bv[DS], Cv[DS];
        {
            const float4* bp4 = (const float4*)(bb + (size_t)l * 80);
            #pragma unroll
            for (int n4 = 0; n4 < 4; ++n4) {
                float4 v = bp4[n4];
                Bv[n4 * 4 + 0] = v.x; Bv[n4 * 4 + 1] = v.y;
                Bv[n4 * 4 + 2] = v.z; Bv[n4 * 4 + 3] = v.w;
            }
            #pragma unroll
            for (int n4 = 0; n4 < 4; ++n4) {
                float4 v = bp4[4 + n4];
                Cv[n4 * 4 + 0] = v.x; Cv[n4 * 4 + 1] = v.y;
                Cv[n4 * 4 + 2] = v.z; Cv[n4 * 4 + 3] = v.w;
            }
        }
        float pv = 0.f;
        #pragma unroll
        for (int n = 0; n < DS; ++n) {
            float dA = expf(dlt * Av[n]);
            float dBu = (dA - 1.f) * invA[n] * Bv[n] * uv;
            s[n] = fmaf(dA, s[n], dBu);
            pv = fmaf(s[n], Cv[n], pv);
        }
        float res = rv / (1.f + expf(-rv));
        yp[(size_t)l * DI] = f2bf((pv + uv * Dv) * res);
    }
}

// ---------------- RMSNorm (plain, for final) ----------------
__global__ __launch_bounds__(256) void rmsnorm_kernel(
    const float* __restrict__ in, const float* __restrict__ w,
    float* __restrict__ outf, unsigned short* __restrict__ outb)
{
    int m = blockIdx.x;
    const float* row = in + (size_t)m * DM;
    float ss = 0.f;
    for (int i = threadIdx.x; i < DM; i += 256) { float v = row[i]; ss = fmaf(v, v, ss); }
    #pragma unroll
    for (int off = 32; off > 0; off >>= 1) ss += __shfl_down(ss, off);
    __shared__ float sred[4];
    __shared__ float sscale;
    int wid = threadIdx.x >> 6;
    if ((threadIdx.x & 63) == 0) sred[wid] = ss;
    __syncthreads();
    if (threadIdx.x == 0) {
        float tot = sred[0] + sred[1] + sred[2] + sred[3];
        sscale = 1.f / sqrtf(tot / (float)DM + 1e-5f);
    }
    __syncthreads();
    float sc = sscale;
    for (int i = threadIdx.x; i < DM; i += 256) {
        float v = row[i] * sc * w[i];
        if (outf) outf[(size_t)m * DM + i] = v;
        if (outb) outb[(size_t)m * DM + i] = f2bf(v);
    }
}

// ---------------- fused: val = p0+p1+out_b+x; x = rmsnorm(val)*w (f32+bf16) ----------------
__global__ __launch_bounds__(256) void rmsnorm_fuse_kernel(
    const float* __restrict__ p0, const float* __restrict__ p1,
    const float* __restrict__ ob, const float* __restrict__ w,
    float* __restrict__ x, unsigned short* __restrict__ x16)
{
    int m = blockIdx.x;
    int tid = threadIdx.x;
    float v0, v1, v2;
    float ss = 0.f;
    {
        size_t base = (size_t)m * DM;
        v0 = p0[base + tid] + p1[base + tid] + x[base + tid] + ob[tid];
        v1 = p0[base + tid + 256] + p1[base + tid + 256] + x[base + tid + 256] + ob[tid + 256];
        v2 = p0[base + tid + 512] + p1[base + tid + 512] + x[base + tid + 512] + ob[tid + 512];
        ss = fmaf(v0, v0, fmaf(v1, v1, v2 * v2));
    }
    #pragma unroll
    for (int off = 32; off > 0; off >>= 1) ss += __shfl_down(ss, off);
    __shared__ float sred[4];
    __shared__ float sscale;
    int wid = tid >> 6;
    if ((tid & 63) == 0) sred[wid] = ss;
    __syncthreads();
    if (tid == 0) {
        float tot = sred[0] + sred[1] + sred[2] + sred[3];
        sscale = 1.f / sqrtf(tot / (float)DM + 1e-5f);
    }
    __syncthreads();
    float sc = sscale;
    size_t base = (size_t)m * DM;
    float o0 = v0 * sc * w[tid];
    float o1 = v1 * sc * w[tid + 256];
    float o2 = v2 * sc * w[tid + 512];
    x[base + tid] = o0;         x16[base + tid] = f2bf(o0);
    x[base + tid + 256] = o1;   x16[base + tid + 256] = f2bf(o1);
    x[base + tid + 512] = o2;   x16[base + tid + 512] = f2bf(o2);
}

// ---------------- launch ----------------
extern "C" void kernel_launch(void* const* d_in, const int* in_sizes, int n_in,
                              void* d_out, int out_size, void* d_ws, size_t ws_size,
                              hipStream_t stream)
{
    const int*   ids      = (const int*)  d_in[0];
    const float* emb      = (const float*)d_in[1];
    const float* in_w     = (const float*)d_in[2];
    const float* in_b     = (const float*)d_in[3];
    const float* conv_w   = (const float*)d_in[4];
    const float* conv_b   = (const float*)d_in[5];
    const float* xproj_w  = (const float*)d_in[6];
    const float* dt_w     = (const float*)d_in[7];
    const float* dt_b     = (const float*)d_in[8];
    const float* A_log    = (const float*)d_in[9];
    const float* Dp       = (const float*)d_in[10];
    const float* out_w    = (const float*)d_in[11];
    const float* out_b    = (const float*)d_in[12];
    const float* norm_w   = (const float*)d_in[13];
    const float* normf_w  = (const float*)d_in[14];
    float* out = (float*)d_out;

    char* wsp = (char*)d_ws;
    auto alloc = [&](size_t bytes) {
        char* p = wsp;
        wsp += (bytes + 255) & ~(size_t)255;
        return p;
    };
    float* x     = (float*)alloc((size_t)MM * DM * 4);
    unsigned short* xr    = (unsigned short*)alloc((size_t)MM * 2 * DI * 2);
    unsigned short* ub    = (unsigned short*)alloc((size_t)MM * DI * 2);
    float* dbc   = (float*)alloc((size_t)MM * 80 * 4);
    unsigned short* dbc48 = (unsigned short*)alloc((size_t)MM * 64 * 2);
    float* part  = (float*)alloc((size_t)KS * MM * 80 * 4);
    unsigned short* delta = (unsigned short*)alloc((size_t)MM * DI * 2);
    float* oprt  = (float*)alloc((size_t)2 * MM * DM * 4);
    float* Pbuf  = (float*)alloc((size_t)BB * NC * DI * DS * 4);
    float* Qbuf  = (float*)alloc((size_t)BB * NC * DI * DS * 4);
    float* Sbuf  = (float*)alloc((size_t)BB * NC * DI * DS * 4);
    unsigned short* x16     = (unsigned short*)alloc((size_t)MM * DM * 2);
    unsigned short* y16     = (unsigned short*)alloc((size_t)MM * DI * 2);
    unsigned short* emb16   = (unsigned short*)alloc((size_t)VPAD * DM * 2);
    unsigned short* in_wT   = (unsigned short*)alloc((size_t)NL * 2 * DI * DM * 2);
    unsigned short* out_wT  = (unsigned short*)alloc((size_t)NL * DM * DI * 2);
    unsigned short* xprojT  = (unsigned short*)alloc((size_t)NL * 128 * DI * 2);
    unsigned short* dtwT    = (unsigned short*)alloc((size_t)NL * DI * 64 * 2);

    emb_convert_kernel<<<((size_t)VPAD * (DM / 8) + 255) / 256, 256, 0, stream>>>(emb, emb16);
    transpose_bf16_kernel<<<dim3(2 * DI / 32, DM / 32, NL), 256, 0, stream>>>(
        in_w, in_wT, DM, 2 * DI);
    transpose_bf16_kernel<<<dim3(DM / 32, DI / 32, NL), 256, 0, stream>>>(
        out_w, out_wT, DI, DM);
    xprojw_convert_kernel<<<dim3(4, DI / 32, NL), 256, 0, stream>>>(xproj_w, xprojT);
    dtw_convert_kernel<<<dim3(DI / 32, 2, NL), 256, 0, stream>>>(dt_w, dtwT);

    embed_kernel<<<MM, 256, 0, stream>>>(ids, emb, x, x16);

    for (int layer = 0; layer < NL; ++layer) {
        const float* lb_in  = in_b    + (size_t)layer * 2 * DI;
        const float* lcw    = conv_w  + (size_t)layer * DI * DC;
        const float* lcb    = conv_b  + (size_t)layer * DI;
        const float* ldtb   = dt_b    + (size_t)layer * DI;
        const float* lAlog  = A_log   + (size_t)layer * DI * DS;
        const float* lDp    = Dp      + (size_t)layer * DI;
        const float* lob    = out_b   + (size_t)layer * DM;
        const float* lnw    = norm_w  + (size_t)layer * DM;
        const unsigned short* lw_inT = in_wT  + (size_t)layer * 2 * DI * DM;
        const unsigned short* lw_outT= out_wT + (size_t)layer * DM * DI;
        const unsigned short* lxT    = xprojT + (size_t)layer * 128 * DI;
        const unsigned short* ldtT   = dtwT   + (size_t)layer * DI * 64;

        // xr = bf16(x @ in_w + in_b)
        gemm_mfma_bt<<<16 * 24, 256, 0, stream>>>(
            x16, lw_inT, lb_in, xr, MM, 2 * DI, DM, 16, 24);

        conv_silu_kernel<<<dim3(DI / 256, LL / CONVL, BB), 256, 0, stream>>>(xr, lcw, lcb, ub);

        // dbc = u @ xproj_w  [MFMA, K-split 8]
        xproj_mfma_part<<<16 * KS, 256, 0, stream>>>(ub, lxT, part);
        xproj_reduce_kernel<<<(MM * 80 + 255) / 256, 256, 0, stream>>>(part, dbc, dbc48);

        // delta = bf16(softplus(dbc48 @ dtwT^T + dt_b))  [MFMA]
        dt_mfma<<<16 * 12, 256, 0, stream>>>(dbc48, ldtT, ldtb, delta);

        scan_reduce_kernel<<<dim3(DI / 256, NC, BB), 256, 0, stream>>>(
            delta, ub, dbc, lAlog, Pbuf, Qbuf);
        scan_combine_kernel<<<(BB * DI * DS) / 256, 256, 0, stream>>>(Pbuf, Qbuf, Sbuf);
        scan_apply_kernel<<<dim3(DI / 256, NC, BB), 256, 0, stream>>>(
            delta, ub, dbc, xr, lAlog, lDp, Sbuf, y16);

        gemm_out_part<<<192, 256, 0, stream>>>(y16, lw_outT, oprt);

        rmsnorm_fuse_kernel<<<MM, 256, 0, stream>>>(
            oprt, oprt + (size_t)MM * DM, lob, lnw, x, x16);
    }

    rmsnorm_kernel<<<MM, 256, 0, stream>>>(x, normf_w, nullptr, x16);

    // logits = xf @ emb^T  (256x128, 2 blocks/CU)
    gemm_logits<<<8 * (VPAD / 128), 512, 0, stream>>>(
        x16, emb16, out, MM, VV, DM, 8, VPAD / 128);
}

// Round 17
// 729.648 us; speedup vs baseline: 1.1835x; 1.1835x over previous
//
#include <hip/hip_runtime.h>
#include <math.h>
#include <stdint.h>

#define BB 2
#define LL 1024
#define DM 768
#define NL 2
#define VV 50264
#define VPAD 50304   // 393 * 128
#define DS 16
#define DI 1536
#define DR 48
#define DC 4
#define MM (BB*LL)

#define CH 32
#define NC (LL/CH)   // 32
#define CONVL 16

#define KS 8         // xproj K-split

#define TS 64
#define KT 16

typedef __attribute__((ext_vector_type(8))) short short8;
typedef __attribute__((ext_vector_type(4))) float f32x4;

#define AS3(p) ((__attribute__((address_space(3))) unsigned int*)(unsigned int)(uintptr_t)(p))
#define AS1(p) ((const __attribute__((address_space(1))) unsigned int*)(uintptr_t)(p))

__device__ __forceinline__ unsigned short f2bf(float v) {
    union { float f; unsigned u; } x; x.f = v;
    unsigned r = x.u + 0x7fffu + ((x.u >> 16) & 1u);
    return (unsigned short)(r >> 16);
}
__device__ __forceinline__ float bf2f(unsigned short h) {
    union { unsigned u; float f; } x; x.u = (unsigned)h << 16;
    return x.f;
}

// ---------------- embedding gather (f32 + bf16) ----------------
__global__ __launch_bounds__(256) void embed_kernel(
    const int* __restrict__ ids, const float* __restrict__ emb,
    float* __restrict__ x, unsigned short* __restrict__ x16)
{
    int m = blockIdx.x;
    int v = ids[m];
    const float* src = emb + (size_t)v * DM;
    float* dst = x + (size_t)m * DM;
    unsigned short* dst16 = x16 + (size_t)m * DM;
    for (int i = threadIdx.x; i < DM; i += 256) {
        float f = src[i];
        dst[i] = f;
        dst16[i] = f2bf(f);
    }
}

// ---------------- emb f32 [VV][DM] -> bf16 [VPAD][DM] (pad rows = 0) ----------------
__global__ __launch_bounds__(256) void emb_convert_kernel(
    const float* __restrict__ emb, unsigned short* __restrict__ out)
{
    size_t i8 = (size_t)blockIdx.x * 256 + threadIdx.x;
    size_t row = i8 / 96;
    size_t col8 = (i8 - row * 96) * 8;
    if (row >= VPAD) return;
    ushort4 o0, o1;
    if (row < VV) {
        const float* p = emb + row * DM + col8;
        float4 v0 = *(const float4*)p;
        float4 v1 = *(const float4*)(p + 4);
        o0.x = f2bf(v0.x); o0.y = f2bf(v0.y); o0.z = f2bf(v0.z); o0.w = f2bf(v0.w);
        o1.x = f2bf(v1.x); o1.y = f2bf(v1.y); o1.z = f2bf(v1.z); o1.w = f2bf(v1.w);
    } else {
        o0 = make_ushort4(0, 0, 0, 0);
        o1 = o0;
    }
    unsigned short* op = out + row * DM + col8;
    *(ushort4*)op = o0;
    *(ushort4*)(op + 4) = o1;
}

// ---------------- transpose+convert: in [L][R][C] f32 -> out [L][C][R] bf16 ----------------
__global__ __launch_bounds__(256) void transpose_bf16_kernel(
    const float* __restrict__ in, unsigned short* __restrict__ out, int R, int C)
{
    __shared__ float t[32][33];
    int l = blockIdx.z;
    int r0 = blockIdx.y * 32, c0 = blockIdx.x * 32;
    int tx = threadIdx.x & 31, ty = threadIdx.x >> 5;
    const float* ip = in + (size_t)l * R * C;
    unsigned short* op = out + (size_t)l * C * R;
    #pragma unroll
    for (int j = 0; j < 32; j += 8)
        t[ty + j][tx] = ip[(size_t)(r0 + ty + j) * C + c0 + tx];
    __syncthreads();
    #pragma unroll
    for (int j = 0; j < 32; j += 8)
        op[(size_t)(c0 + ty + j) * R + r0 + tx] = f2bf(t[tx][ty + j]);
}

// ---------------- 128x128 MFMA GEMM (in-proj), bf16 output ----------------
__global__ __launch_bounds__(256) void gemm_mfma_bt(
    const unsigned short* __restrict__ A, const unsigned short* __restrict__ B,
    const float* __restrict__ bias, unsigned short* __restrict__ C16,
    int M, int N, int K, int MT, int NTILES)
{
    int T = MT * NTILES;
    int q = T >> 3, r = T & 7;
    int orig = blockIdx.x;
    int xcd = orig & 7, u = orig >> 3;
    int wg = (xcd < r ? xcd * (q + 1) : r * (q + 1) + (xcd - r) * q) + u;
    int mt = wg % MT, nt = wg / MT;

    __shared__ unsigned short As[3][128 * 32];
    __shared__ unsigned short Bs[3][128 * 32];
    int tid = threadIdx.x;
    int w = tid >> 6, lane = tid & 63;
    int m0 = mt * 128, n0 = nt * 128;

    int rA = lane >> 2;
    int kb = (lane & 3) * 8;
    const unsigned short* gA0 = A + (size_t)(m0 + w * 16 + rA) * K + kb;
    const unsigned short* gA1 = gA0 + (size_t)64 * K;
    const unsigned short* gB0 = B + (size_t)(n0 + w * 16 + rA) * K + kb;
    const unsigned short* gB1 = gB0 + (size_t)64 * K;

    int lr = lane & 15, lk = lane >> 4;
    int wr = (w >> 1) * 64, wc = (w & 1) * 64;

    f32x4 acc[4][4] = {};

#define STAGE(k0, buf) do { \
    __builtin_amdgcn_global_load_lds(AS1(gA0 + (k0)), AS3(&As[buf][(w * 16) * 32]), 16, 0, 0); \
    __builtin_amdgcn_global_load_lds(AS1(gA1 + (k0)), AS3(&As[buf][(64 + w * 16) * 32]), 16, 0, 0); \
    __builtin_amdgcn_global_load_lds(AS1(gB0 + (k0)), AS3(&Bs[buf][(w * 16) * 32]), 16, 0, 0); \
    __builtin_amdgcn_global_load_lds(AS1(gB1 + (k0)), AS3(&Bs[buf][(64 + w * 16) * 32]), 16, 0, 0); \
} while (0)

#define COMPUTE(buf) do { \
    short8 a[4], b[4]; \
    _Pragma("unroll") \
    for (int f = 0; f < 4; ++f) \
        a[f] = *(const short8*)&As[buf][(wr + f * 16 + lr) * 32 + lk * 8]; \
    _Pragma("unroll") \
    for (int f = 0; f < 4; ++f) \
        b[f] = *(const short8*)&Bs[buf][(wc + f * 16 + lr) * 32 + lk * 8]; \
    _Pragma("unroll") \
    for (int i = 0; i < 4; ++i) \
        _Pragma("unroll") \
        for (int j = 0; j < 4; ++j) \
            acc[i][j] = __builtin_amdgcn_mfma_f32_16x16x32_bf16(a[i], b[j], acc[i][j], 0, 0, 0); \
} while (0)

    int nsteps = K / 32;
    STAGE(0, 0);
    STAGE(32, 1);
    asm volatile("s_waitcnt vmcnt(4)" ::: "memory");
    __builtin_amdgcn_s_barrier();
    __builtin_amdgcn_sched_barrier(0);

    for (int t = 0; t < nsteps; ++t) {
        int cur = t % 3;
        if (t + 2 < nsteps)
            STAGE((t + 2) * 32, (t + 2) % 3);
        COMPUTE(cur);
        if (t + 1 < nsteps) {
            if (t + 2 < nsteps)
                asm volatile("s_waitcnt vmcnt(4)" ::: "memory");
            else
                asm volatile("s_waitcnt vmcnt(0)" ::: "memory");
            __builtin_amdgcn_s_barrier();
            __builtin_amdgcn_sched_barrier(0);
        }
    }

#undef STAGE
#undef COMPUTE

    #pragma unroll
    for (int i = 0; i < 4; ++i) {
        int row = m0 + wr + i * 16 + lk * 4;
        #pragma unroll
        for (int j = 0; j < 4; ++j) {
            int col = n0 + wc + j * 16 + lr;
            if (col < N) {
                float bv = bias ? bias[col] : 0.f;
                #pragma unroll
                for (int r2 = 0; r2 < 4; ++r2) {
                    float v = acc[i][j][r2] + bv;
                    C16[(size_t)(row + r2) * N + col] = f2bf(v);
                }
            }
        }
    }
}

// ---------------- out-proj K-split partial GEMM ----------------
__global__ __launch_bounds__(256) void gemm_out_part(
    const unsigned short* __restrict__ A, const unsigned short* __restrict__ B,
    float* __restrict__ part)
{
    const int T = 16 * 6 * 2;
    int q = T >> 3;
    int orig = blockIdx.x;
    int xcd = orig & 7, u = orig >> 3;
    int wg = xcd * q + u;
    int mt = wg % 16;
    int rest = wg / 16;
    int nt = rest % 6, z = rest / 6;

    __shared__ unsigned short As[3][128 * 32];
    __shared__ unsigned short Bs[3][128 * 32];
    int tid = threadIdx.x;
    int w = tid >> 6, lane = tid & 63;
    int m0 = mt * 128, n0 = nt * 128;
    int kh = z * 768;

    int rA = lane >> 2;
    int kb = (lane & 3) * 8;
    const unsigned short* gA0 = A + (size_t)(m0 + w * 16 + rA) * DI + kh + kb;
    const unsigned short* gA1 = gA0 + (size_t)64 * DI;
    const unsigned short* gB0 = B + (size_t)(n0 + w * 16 + rA) * DI + kh + kb;
    const unsigned short* gB1 = gB0 + (size_t)64 * DI;

    int lr = lane & 15, lk = lane >> 4;
    int wr = (w >> 1) * 64, wc = (w & 1) * 64;

    f32x4 acc[4][4] = {};

#define STAGE(k0, buf) do { \
    __builtin_amdgcn_global_load_lds(AS1(gA0 + (k0)), AS3(&As[buf][(w * 16) * 32]), 16, 0, 0); \
    __builtin_amdgcn_global_load_lds(AS1(gA1 + (k0)), AS3(&As[buf][(64 + w * 16) * 32]), 16, 0, 0); \
    __builtin_amdgcn_global_load_lds(AS1(gB0 + (k0)), AS3(&Bs[buf][(w * 16) * 32]), 16, 0, 0); \
    __builtin_amdgcn_global_load_lds(AS1(gB1 + (k0)), AS3(&Bs[buf][(64 + w * 16) * 32]), 16, 0, 0); \
} while (0)

#define COMPUTE(buf) do { \
    short8 a[4], b[4]; \
    _Pragma("unroll") \
    for (int f = 0; f < 4; ++f) \
        a[f] = *(const short8*)&As[buf][(wr + f * 16 + lr) * 32 + lk * 8]; \
    _Pragma("unroll") \
    for (int f = 0; f < 4; ++f) \
        b[f] = *(const short8*)&Bs[buf][(wc + f * 16 + lr) * 32 + lk * 8]; \
    _Pragma("unroll") \
    for (int i = 0; i < 4; ++i) \
        _Pragma("unroll") \
        for (int j = 0; j < 4; ++j) \
            acc[i][j] = __builtin_amdgcn_mfma_f32_16x16x32_bf16(a[i], b[j], acc[i][j], 0, 0, 0); \
} while (0)

    const int nsteps = 768 / 32;   // 24
    STAGE(0, 0);
    STAGE(32, 1);
    asm volatile("s_waitcnt vmcnt(4)" ::: "memory");
    __builtin_amdgcn_s_barrier();
    __builtin_amdgcn_sched_barrier(0);

    for (int t = 0; t < nsteps; ++t) {
        int cur = t % 3;
        if (t + 2 < nsteps)
            STAGE((t + 2) * 32, (t + 2) % 3);
        COMPUTE(cur);
        if (t + 1 < nsteps) {
            if (t + 2 < nsteps)
                asm volatile("s_waitcnt vmcnt(4)" ::: "memory");
            else
                asm volatile("s_waitcnt vmcnt(0)" ::: "memory");
            __builtin_amdgcn_s_barrier();
            __builtin_amdgcn_sched_barrier(0);
        }
    }

#undef STAGE
#undef COMPUTE

    float* op = part + (size_t)z * MM * DM;
    #pragma unroll
    for (int i = 0; i < 4; ++i) {
        int row = m0 + wr + i * 16 + lk * 4;
        #pragma unroll
        for (int j = 0; j < 4; ++j) {
            int col = n0 + wc + j * 16 + lr;
            #pragma unroll
            for (int r2 = 0; r2 < 4; ++r2)
                op[(size_t)(row + r2) * DM + col] = acc[i][j][r2];
        }
    }
}

// ---------------- 256x128 phase-split MFMA GEMM (logits) ----------------
__global__ __launch_bounds__(512) void gemm_logits(
    const unsigned short* __restrict__ A, const unsigned short* __restrict__ B,
    float* __restrict__ C, int M, int N, int K, int MT, int NTILES)
{
    int T = MT * NTILES;
    int q = T >> 3, r = T & 7;
    int orig = blockIdx.x;
    int xcd = orig & 7, u = orig >> 3;
    int wg = (xcd < r ? xcd * (q + 1) : r * (q + 1) + (xcd - r) * q) + u;
    int mt = wg % MT, nt = wg / MT;

    __shared__ unsigned short As[3][256 * 32];
    __shared__ unsigned short Bs[3][128 * 32];
    int tid = threadIdx.x;
    int w = tid >> 6, lane = tid & 63;
    int wm = w >> 1, wn = w & 1;
    int m0 = mt * 256, n0 = nt * 128;

    int srow = tid >> 2;
    int schunk = (tid & 3) ^ ((srow & 3) ^ ((srow >> 2) & 3));
    const unsigned short* gA0 = A + (size_t)(m0 + srow) * K + schunk * 8;
    const unsigned short* gA1 = gA0 + (size_t)128 * K;
    const unsigned short* gB0 = B + (size_t)(n0 + srow) * K + schunk * 8;

    int lr = lane & 15, lk = lane >> 4;
    int rc = (lk ^ ((lr & 3) ^ ((lr >> 2) & 3))) * 8;

    f32x4 acc[4][4] = {};

#define STAGE_A(k0, buf) do { \
    __builtin_amdgcn_global_load_lds(AS1(gA0 + (k0)), AS3(&As[buf][(w * 16) * 32]), 16, 0, 0); \
    __builtin_amdgcn_global_load_lds(AS1(gA1 + (k0)), AS3(&As[buf][(128 + w * 16) * 32]), 16, 0, 0); \
} while (0)
#define STAGE_B(k0, buf) do { \
    __builtin_amdgcn_global_load_lds(AS1(gB0 + (k0)), AS3(&Bs[buf][(w * 16) * 32]), 16, 0, 0); \
} while (0)

    int nsteps = K / 32;

    STAGE_A(0, 0); STAGE_B(0, 0);
    STAGE_A(32, 1); STAGE_B(32, 1);
    asm volatile("s_waitcnt vmcnt(3)" ::: "memory");
    __builtin_amdgcn_s_barrier();
    __builtin_amdgcn_sched_barrier(0);

    for (int t = 0; t < nsteps; ++t) {
        int s = t % 3;
        int sn = (t + 2) % 3;
        bool stage2 = (t + 2) < nsteps;
        short8 av[2], bv[4];

        #pragma unroll
        for (int f = 0; f < 2; ++f)
            av[f] = *(const short8*)&As[s][(wm * 64 + f * 16 + lr) * 32 + rc];
        #pragma unroll
        for (int f = 0; f < 4; ++f)
            bv[f] = *(const short8*)&Bs[s][(wn * 64 + f * 16 + lr) * 32 + rc];
        if (stage2) STAGE_A((t + 2) * 32, sn);
        __builtin_amdgcn_s_barrier();
        asm volatile("s_waitcnt lgkmcnt(0)" ::: "memory");
        __builtin_amdgcn_sched_barrier(0);
        __builtin_amdgcn_s_setprio(1);
        #pragma unroll
        for (int i = 0; i < 2; ++i)
            #pragma unroll
            for (int j = 0; j < 4; ++j)
                acc[i][j] = __builtin_amdgcn_mfma_f32_16x16x32_bf16(av[i], bv[j], acc[i][j], 0, 0, 0);
        __builtin_amdgcn_s_setprio(0);
        __builtin_amdgcn_s_barrier();

        #pragma unroll
        for (int f = 0; f < 2; ++f)
            av[f] = *(const short8*)&As[s][(wm * 64 + (2 + f) * 16 + lr) * 32 + rc];
        if (stage2) STAGE_B((t + 2) * 32, sn);
        __builtin_amdgcn_s_barrier();
        asm volatile("s_waitcnt lgkmcnt(0)" ::: "memory");
        __builtin_amdgcn_sched_barrier(0);
        __builtin_amdgcn_s_setprio(1);
        #pragma unroll
        for (int i = 0; i < 2; ++i)
            #pragma unroll
            for (int j = 0; j < 4; ++j)
                acc[2 + i][j] = __builtin_amdgcn_mfma_f32_16x16x32_bf16(av[i], bv[j], acc[2 + i][j], 0, 0, 0);
        __builtin_amdgcn_s_setprio(0);

        if (t + 1 < nsteps) {
            if (stage2)
                asm volatile("s_waitcnt vmcnt(3)" ::: "memory");
            else
                asm volatile("s_waitcnt vmcnt(0)" ::: "memory");
            __builtin_amdgcn_s_barrier();
            __builtin_amdgcn_sched_barrier(0);
        }
    }

#undef STAGE_A
#undef STAGE_B

    #pragma unroll
    for (int i = 0; i < 4; ++i) {
        int row = m0 + wm * 64 + i * 16 + lk * 4;
        #pragma unroll
        for (int j = 0; j < 4; ++j) {
            int col = n0 + wn * 64 + j * 16 + lr;
            if (col < N) {
                #pragma unroll
                for (int r2 = 0; r2 < 4; ++r2)
                    C[(size_t)(row + r2) * N + col] = acc[i][j][r2];
            }
        }
    }
}

// ---------------- dt GEMM: delta = softplus(dbc[:, :48] @ dt_w + dt_b), bf16 out ----------------
__global__ __launch_bounds__(256) void dt_kernel(
    const float* __restrict__ A, const float* __restrict__ Bm,
    const float* __restrict__ bias, unsigned short* __restrict__ C16,
    int M, int N, int K, int lda)
{
    __shared__ float As[KT][TS + 4];
    __shared__ float Bs[KT][TS + 4];
    int tid = threadIdx.x;
    int tx = tid & 15, ty = tid >> 4;
    int m0 = blockIdx.y * TS;
    int n0 = blockIdx.x * TS;
    float acc[4][4] = {};

    for (int k0 = 0; k0 < K; k0 += KT) {
        {
            int i = tid >> 2;
            int k4 = (tid & 3) * 4;
            float4 v = *(const float4*)(A + (size_t)(m0 + i) * lda + k0 + k4);
            As[k4 + 0][i] = v.x; As[k4 + 1][i] = v.y;
            As[k4 + 2][i] = v.z; As[k4 + 3][i] = v.w;
        }
        {
            int k = tid >> 4;
            int j4 = (tid & 15) * 4;
            float4 v = *(const float4*)(Bm + (size_t)(k0 + k) * N + n0 + j4);
            Bs[k][j4 + 0] = v.x; Bs[k][j4 + 1] = v.y;
            Bs[k][j4 + 2] = v.z; Bs[k][j4 + 3] = v.w;
        }
        __syncthreads();
        #pragma unroll
        for (int k = 0; k < KT; ++k) {
            float a[4], b[4];
            #pragma unroll
            for (int q2 = 0; q2 < 4; ++q2) a[q2] = As[k][ty * 4 + q2];
            #pragma unroll
            for (int q2 = 0; q2 < 4; ++q2) b[q2] = Bs[k][tx * 4 + q2];
            #pragma unroll
            for (int i = 0; i < 4; ++i)
                #pragma unroll
                for (int j = 0; j < 4; ++j)
                    acc[i][j] = fmaf(a[i], b[j], acc[i][j]);
        }
        __syncthreads();
    }

    #pragma unroll
    for (int i = 0; i < 4; ++i) {
        int m = m0 + ty * 4 + i;
        #pragma unroll
        for (int j = 0; j < 4; ++j) {
            int n = n0 + tx * 4 + j;
            float v = acc[i][j] + bias[n];
            v = fmaxf(v, 0.f) + log1pf(expf(-fabsf(v)));
            C16[(size_t)m * N + n] = f2bf(v);
        }
    }
}

// ---------------- xproj partial GEMM (A = bf16 u) ----------------
__global__ __launch_bounds__(256) void xproj_part_kernel(
    const unsigned short* __restrict__ A, const float* __restrict__ Bm,
    float* __restrict__ part)
{
    __shared__ float As[KT][TS + 4];
    __shared__ float Bs[KT][TS + 4];
    int tid = threadIdx.x;
    int tx = tid & 15, ty = tid >> 4;
    int m0 = blockIdx.y * TS;
    int n0 = blockIdx.x * TS;
    int kbeg = blockIdx.z * (DI / KS);
    const int N = 80;
    float acc[4][4] = {};

    for (int k0 = kbeg; k0 < kbeg + DI / KS; k0 += KT) {
        {
            int i = tid >> 2;
            int k4 = (tid & 3) * 4;
            ushort4 hv = *(const ushort4*)(A + (size_t)(m0 + i) * DI + k0 + k4);
            As[k4 + 0][i] = bf2f(hv.x); As[k4 + 1][i] = bf2f(hv.y);
            As[k4 + 2][i] = bf2f(hv.z); As[k4 + 3][i] = bf2f(hv.w);
        }
        {
            int k = tid >> 4;
            int j4 = (tid & 15) * 4;
            int n = n0 + j4;
            const float* p = Bm + (size_t)(k0 + k) * N + n;
            float4 v;
            if (n + 3 < N) {
                v = *(const float4*)p;
            } else {
                v.x = (n + 0 < N) ? p[0] : 0.f;
                v.y = (n + 1 < N) ? p[1] : 0.f;
                v.z = (n + 2 < N) ? p[2] : 0.f;
                v.w = (n + 3 < N) ? p[3] : 0.f;
            }
            Bs[k][j4 + 0] = v.x; Bs[k][j4 + 1] = v.y;
            Bs[k][j4 + 2] = v.z; Bs[k][j4 + 3] = v.w;
        }
        __syncthreads();
        #pragma unroll
        for (int k = 0; k < KT; ++k) {
            float a[4], b[4];
            #pragma unroll
            for (int q2 = 0; q2 < 4; ++q2) a[q2] = As[k][ty * 4 + q2];
            #pragma unroll
            for (int q2 = 0; q2 < 4; ++q2) b[q2] = Bs[k][tx * 4 + q2];
            #pragma unroll
            for (int i = 0; i < 4; ++i)
                #pragma unroll
                for (int j = 0; j < 4; ++j)
                    acc[i][j] = fmaf(a[i], b[j], acc[i][j]);
        }
        __syncthreads();
    }

    float* op = part + (size_t)blockIdx.z * MM * 80;
    #pragma unroll
    for (int i = 0; i < 4; ++i) {
        int m = m0 + ty * 4 + i;
        #pragma unroll
        for (int j = 0; j < 4; ++j) {
            int n = n0 + tx * 4 + j;
            if (n < 80) op[(size_t)m * 80 + n] = acc[i][j];
        }
    }
}

__global__ __launch_bounds__(256) void xproj_reduce_kernel(
    const float* __restrict__ part, float* __restrict__ dbc)
{
    int i = blockIdx.x * 256 + threadIdx.x;
    if (i >= MM * 80) return;
    float s = 0.f;
    #pragma unroll
    for (int z = 0; z < KS; ++z) s += part[(size_t)z * MM * 80 + i];
    dbc[i] = s;
}

// ---------------- causal depthwise conv1d + SiLU (bf16 in/out) ----------------
__global__ __launch_bounds__(256) void conv_silu_kernel(
    const unsigned short* __restrict__ xr, const float* __restrict__ cw,
    const float* __restrict__ cb, unsigned short* __restrict__ u)
{
    int d = blockIdx.x * 256 + threadIdx.x;
    int l0 = blockIdx.y * CONVL;
    int b = blockIdx.z;
    const float4 wv = *(const float4*)(cw + (size_t)d * DC);
    float bias = cb[d];
    const unsigned short* xp = xr + ((size_t)(b * LL + l0)) * (2 * DI) + d;
    unsigned short* up = u + ((size_t)(b * LL + l0)) * DI + d;
    const ptrdiff_t RS = 2 * DI;
    float xm3 = (l0 >= 3) ? bf2f(xp[-3 * RS]) : 0.f;
    float xm2 = (l0 >= 2) ? bf2f(xp[-2 * RS]) : 0.f;
    float xm1 = (l0 >= 1) ? bf2f(xp[-1 * RS]) : 0.f;
    #pragma unroll
    for (int l = 0; l < CONVL; ++l) {
        float xc = bf2f(xp[(ptrdiff_t)l * RS]);
        float acc = bias;
        acc = fmaf(wv.x, xm3, acc);
        acc = fmaf(wv.y, xm2, acc);
        acc = fmaf(wv.z, xm1, acc);
        acc = fmaf(wv.w, xc, acc);
        float s = acc / (1.f + expf(-acc));
        up[(size_t)l * DI] = f2bf(s);
        xm3 = xm2; xm2 = xm1; xm1 = xc;
    }
}

// ---------------- chunked selective scan, lane-per-d layout ----------------
__global__ __launch_bounds__(256) void scan_reduce_kernel(
    const unsigned short* __restrict__ delta, const unsigned short* __restrict__ u,
    const float* __restrict__ dbc, const float* __restrict__ A_log,
    float* __restrict__ P, float* __restrict__ Q)
{
    int d = blockIdx.x * 256 + threadIdx.x;
    int c = blockIdx.y;
    int b = blockIdx.z;

    float Av[DS], invA[DS];
    {
        const float4* ap = (const float4*)(A_log + (size_t)d * DS);
        #pragma unroll
        for (int n4 = 0; n4 < 4; ++n4) {
            float4 a = ap[n4];
            Av[n4 * 4 + 0] = -expf(a.x); Av[n4 * 4 + 1] = -expf(a.y);
            Av[n4 * 4 + 2] = -expf(a.z); Av[n4 * 4 + 3] = -expf(a.w);
        }
        #pragma unroll
        for (int n = 0; n < DS; ++n) invA[n] = 1.f / (Av[n] + 1e-7f);
    }

    float p[DS], s[DS];
    #pragma unroll
    for (int n = 0; n < DS; ++n) { p[n] = 1.f; s[n] = 0.f; }

    const unsigned short* dp = delta + ((size_t)b * LL + c * CH) * DI + d;
    const unsigned short* up = u     + ((size_t)b * LL + c * CH) * DI + d;
    const float* bb = dbc + ((size_t)b * LL + c * CH) * 80 + DR;

    for (int l = 0; l < CH; ++l) {
        float dlt = bf2f(dp[(size_t)l * DI]);
        float uv  = bf2f(up[(size_t)l * DI]);
        float Bv[DS];
        {
            const float4* bp4 = (const float4*)(bb + (size_t)l * 80);
            #pragma unroll
            for (int n4 = 0; n4 < 4; ++n4) {
                float4 v = bp4[n4];
                Bv[n4 * 4 + 0] = v.x; Bv[n4 * 4 + 1] = v.y;
                Bv[n4 * 4 + 2] = v.z; Bv[n4 * 4 + 3] = v.w;
            }
        }
        #pragma unroll
        for (int n = 0; n < DS; ++n) {
            float dA = expf(dlt * Av[n]);
            float dBu = (dA - 1.f) * invA[n] * Bv[n] * uv;
            p[n] *= dA;
            s[n] = fmaf(dA, s[n], dBu);
        }
    }

    float* Pp = P + (((size_t)b * NC + c) * DI + d) * DS;
    float* Qp = Q + (((size_t)b * NC + c) * DI + d) * DS;
    #pragma unroll
    for (int n4 = 0; n4 < 4; ++n4) {
        ((float4*)Pp)[n4] = make_float4(p[n4 * 4 + 0], p[n4 * 4 + 1], p[n4 * 4 + 2], p[n4 * 4 + 3]);
        ((float4*)Qp)[n4] = make_float4(s[n4 * 4 + 0], s[n4 * 4 + 1], s[n4 * 4 + 2], s[n4 * 4 + 3]);
    }
}

__global__ __launch_bounds__(256) void scan_combine_kernel(
    const float* __restrict__ P, const float* __restrict__ Q, float* __restrict__ Sinit)
{
    int t = blockIdx.x * 256 + threadIdx.x;
    int b = t / (DI * DS);
    int dn = t - b * (DI * DS);
    float s = 0.f;
    for (int c = 0; c < NC; ++c) {
        size_t idx = ((size_t)b * NC + c) * (DI * DS) + dn;
        Sinit[idx] = s;
        s = fmaf(P[idx], s, Q[idx]);
    }
}

__global__ __launch_bounds__(256) void scan_apply_kernel(
    const unsigned short* __restrict__ delta, const unsigned short* __restrict__ u,
    const float* __restrict__ dbc, const unsigned short* __restrict__ xr,
    const float* __restrict__ A_log, const float* __restrict__ Dp,
    const float* __restrict__ Sinit, unsigned short* __restrict__ y16)
{
    int d = blockIdx.x * 256 + threadIdx.x;
    int c = blockIdx.y;
    int b = blockIdx.z;

    float Av[DS], invA[DS];
    {
        const float4* ap = (const float4*)(A_log + (size_t)d * DS);
        #pragma unroll
        for (int n4 = 0; n4 < 4; ++n4) {
            float4 a = ap[n4];
            Av[n4 * 4 + 0] = -expf(a.x); Av[n4 * 4 + 1] = -expf(a.y);
            Av[n4 * 4 + 2] = -expf(a.z); Av[n4 * 4 + 3] = -expf(a.w);
        }
        #pragma unroll
        for (int n = 0; n < DS; ++n) invA[n] = 1.f / (Av[n] + 1e-7f);
    }
    float Dv = Dp[d];

    float s[DS];
    {
        const float4* Sp = (const float4*)(Sinit + (((size_t)b * NC + c) * DI + d) * DS);
        #pragma unroll
        for (int n4 = 0; n4 < 4; ++n4) {
            float4 sw = Sp[n4];
            s[n4 * 4 + 0] = sw.x; s[n4 * 4 + 1] = sw.y;
            s[n4 * 4 + 2] = sw.z; s[n4 * 4 + 3] = sw.w;
        }
    }

    const unsigned short* dp = delta + ((size_t)b * LL + c * CH) * DI + d;
    const unsigned short* up = u     + ((size_t)b * LL + c * CH) * DI + d;
    const unsigned short* xp = xr    + ((size_t)b * LL + c * CH) * (2 * DI) + DI + d;
    const float* bb = dbc + ((size_t)b * LL + c * CH) * 80 + DR;
    unsigned short* yp = y16 + ((size_t)b * LL + c * CH) * DI + d;

    for (int l = 0; l < CH; ++l) {
        float dlt = bf2f(dp[(size_t)l * DI]);
        float uv  = bf2f(up[(size_t)l * DI]);
        float rv  = bf2f(xp[(size_t)l * (2 * DI)]);
        float Bv[DS], Cv[DS];
        {
            const float4* bp4 = (const float4*)(bb + (size_t)l * 80);
            #pragma unroll
            for (int n4 = 0; n4 < 4; ++n4) {
                float4 v = bp4[n4];
                Bv[n4 * 4 + 0] = v.x; Bv[n4 * 4 + 1] = v.y;
                Bv[n4 * 4 + 2] = v.z; Bv[n4 * 4 + 3] = v.w;
            }
            #pragma unroll
            for (int n4 = 0; n4 < 4; ++n4) {
                float4 v = bp4[4 + n4];
                Cv[n4 * 4 + 0] = v.x; Cv[n4 * 4 + 1] = v.y;
                Cv[n4 * 4 + 2] = v.z; Cv[n4 * 4 + 3] = v.w;
            }
        }
        float pv = 0.f;
        #pragma unroll
        for (int n = 0; n < DS; ++n) {
            float dA = expf(dlt * Av[n]);
            float dBu = (dA - 1.f) * invA[n] * Bv[n] * uv;
            s[n] = fmaf(dA, s[n], dBu);
            pv = fmaf(s[n], Cv[n], pv);
        }
        float res = rv / (1.f + expf(-rv));
        yp[(size_t)l * DI] = f2bf((pv + uv * Dv) * res);
    }
}

// ---------------- RMSNorm (plain, for final) ----------------
__global__ __launch_bounds__(256) void rmsnorm_kernel(
    const float* __restrict__ in, const float* __restrict__ w,
    float* __restrict__ outf, unsigned short* __restrict__ outb)
{
    int m = blockIdx.x;
    const float* row = in + (size_t)m * DM;
    float ss = 0.f;
    for (int i = threadIdx.x; i < DM; i += 256) { float v = row[i]; ss = fmaf(v, v, ss); }
    #pragma unroll
    for (int off = 32; off > 0; off >>= 1) ss += __shfl_down(ss, off);
    __shared__ float sred[4];
    __shared__ float sscale;
    int wid = threadIdx.x >> 6;
    if ((threadIdx.x & 63) == 0) sred[wid] = ss;
    __syncthreads();
    if (threadIdx.x == 0) {
        float tot = sred[0] + sred[1] + sred[2] + sred[3];
        sscale = 1.f / sqrtf(tot / (float)DM + 1e-5f);
    }
    __syncthreads();
    float sc = sscale;
    for (int i = threadIdx.x; i < DM; i += 256) {
        float v = row[i] * sc * w[i];
        if (outf) outf[(size_t)m * DM + i] = v;
        if (outb) outb[(size_t)m * DM + i] = f2bf(v);
    }
}

// ---------------- fused: val = p0+p1+out_b+x; x = rmsnorm(val)*w (f32+bf16) ----------------
__global__ __launch_bounds__(256) void rmsnorm_fuse_kernel(
    const float* __restrict__ p0, const float* __restrict__ p1,
    const float* __restrict__ ob, const float* __restrict__ w,
    float* __restrict__ x, unsigned short* __restrict__ x16)
{
    int m = blockIdx.x;
    int tid = threadIdx.x;
    float v0, v1, v2;
    float ss = 0.f;
    {
        size_t base = (size_t)m * DM;
        v0 = p0[base + tid] + p1[base + tid] + x[base + tid] + ob[tid];
        v1 = p0[base + tid + 256] + p1[base + tid + 256] + x[base + tid + 256] + ob[tid + 256];
        v2 = p0[base + tid + 512] + p1[base + tid + 512] + x[base + tid + 512] + ob[tid + 512];
        ss = fmaf(v0, v0, fmaf(v1, v1, v2 * v2));
    }
    #pragma unroll
    for (int off = 32; off > 0; off >>= 1) ss += __shfl_down(ss, off);
    __shared__ float sred[4];
    __shared__ float sscale;
    int wid = tid >> 6;
    if ((tid & 63) == 0) sred[wid] = ss;
    __syncthreads();
    if (tid == 0) {
        float tot = sred[0] + sred[1] + sred[2] + sred[3];
        sscale = 1.f / sqrtf(tot / (float)DM + 1e-5f);
    }
    __syncthreads();
    float sc = sscale;
    size_t base = (size_t)m * DM;
    float o0 = v0 * sc * w[tid];
    float o1 = v1 * sc * w[tid + 256];
    float o2 = v2 * sc * w[tid + 512];
    x[base + tid] = o0;         x16[base + tid] = f2bf(o0);
    x[base + tid + 256] = o1;   x16[base + tid + 256] = f2bf(o1);
    x[base + tid + 512] = o2;   x16[base + tid + 512] = f2bf(o2);
}

// ---------------- launch ----------------
extern "C" void kernel_launch(void* const* d_in, const int* in_sizes, int n_in,
                              void* d_out, int out_size, void* d_ws, size_t ws_size,
                              hipStream_t stream)
{
    const int*   ids      = (const int*)  d_in[0];
    const float* emb      = (const float*)d_in[1];
    const float* in_w     = (const float*)d_in[2];
    const float* in_b     = (const float*)d_in[3];
    const float* conv_w   = (const float*)d_in[4];
    const float* conv_b   = (const float*)d_in[5];
    const float* xproj_w  = (const float*)d_in[6];
    const float* dt_w     = (const float*)d_in[7];
    const float* dt_b     = (const float*)d_in[8];
    const float* A_log    = (const float*)d_in[9];
    const float* Dp       = (const float*)d_in[10];
    const float* out_w    = (const float*)d_in[11];
    const float* out_b    = (const float*)d_in[12];
    const float* norm_w   = (const float*)d_in[13];
    const float* normf_w  = (const float*)d_in[14];
    float* out = (float*)d_out;

    char* wsp = (char*)d_ws;
    auto alloc = [&](size_t bytes) {
        char* p = wsp;
        wsp += (bytes + 255) & ~(size_t)255;
        return p;
    };
    float* x     = (float*)alloc((size_t)MM * DM * 4);
    unsigned short* xr    = (unsigned short*)alloc((size_t)MM * 2 * DI * 2);
    unsigned short* ub    = (unsigned short*)alloc((size_t)MM * DI * 2);
    float* dbc   = (float*)alloc((size_t)MM * 80 * 4);
    float* part  = (float*)alloc((size_t)KS * MM * 80 * 4);
    unsigned short* delta = (unsigned short*)alloc((size_t)MM * DI * 2);
    float* oprt  = (float*)alloc((size_t)2 * MM * DM * 4);
    float* Pbuf  = (float*)alloc((size_t)BB * NC * DI * DS * 4);
    float* Qbuf  = (float*)alloc((size_t)BB * NC * DI * DS * 4);
    float* Sbuf  = (float*)alloc((size_t)BB * NC * DI * DS * 4);
    unsigned short* x16     = (unsigned short*)alloc((size_t)MM * DM * 2);
    unsigned short* y16     = (unsigned short*)alloc((size_t)MM * DI * 2);
    unsigned short* emb16   = (unsigned short*)alloc((size_t)VPAD * DM * 2);
    unsigned short* in_wT   = (unsigned short*)alloc((size_t)NL * 2 * DI * DM * 2);
    unsigned short* out_wT  = (unsigned short*)alloc((size_t)NL * DM * DI * 2);

    emb_convert_kernel<<<((size_t)VPAD * (DM / 8) + 255) / 256, 256, 0, stream>>>(emb, emb16);
    transpose_bf16_kernel<<<dim3(2 * DI / 32, DM / 32, NL), 256, 0, stream>>>(
        in_w, in_wT, DM, 2 * DI);
    transpose_bf16_kernel<<<dim3(DM / 32, DI / 32, NL), 256, 0, stream>>>(
        out_w, out_wT, DI, DM);

    embed_kernel<<<MM, 256, 0, stream>>>(ids, emb, x, x16);

    for (int layer = 0; layer < NL; ++layer) {
        const float* lb_in  = in_b    + (size_t)layer * 2 * DI;
        const float* lcw    = conv_w  + (size_t)layer * DI * DC;
        const float* lcb    = conv_b  + (size_t)layer * DI;
        const float* lxw    = xproj_w + (size_t)layer * DI * (DR + 2 * DS);
        const float* ldtw   = dt_w    + (size_t)layer * DR * DI;
        const float* ldtb   = dt_b    + (size_t)layer * DI;
        const float* lAlog  = A_log   + (size_t)layer * DI * DS;
        const float* lDp    = Dp      + (size_t)layer * DI;
        const float* lob    = out_b   + (size_t)layer * DM;
        const float* lnw    = norm_w  + (size_t)layer * DM;
        const unsigned short* lw_inT = in_wT  + (size_t)layer * 2 * DI * DM;
        const unsigned short* lw_outT= out_wT + (size_t)layer * DM * DI;

        // xr = bf16(x @ in_w + in_b)
        gemm_mfma_bt<<<16 * 24, 256, 0, stream>>>(
            x16, lw_inT, lb_in, xr, MM, 2 * DI, DM, 16, 24);

        conv_silu_kernel<<<dim3(DI / 256, LL / CONVL, BB), 256, 0, stream>>>(xr, lcw, lcb, ub);

        xproj_part_kernel<<<dim3(2, MM / TS, KS), 256, 0, stream>>>(ub, lxw, part);
        xproj_reduce_kernel<<<(MM * 80 + 255) / 256, 256, 0, stream>>>(part, dbc);

        dt_kernel<<<dim3(DI / TS, MM / TS), 256, 0, stream>>>(
            dbc, ldtw, ldtb, delta, MM, DI, DR, DR + 2 * DS);

        scan_reduce_kernel<<<dim3(DI / 256, NC, BB), 256, 0, stream>>>(
            delta, ub, dbc, lAlog, Pbuf, Qbuf);
        scan_combine_kernel<<<(BB * DI * DS) / 256, 256, 0, stream>>>(Pbuf, Qbuf, Sbuf);
        scan_apply_kernel<<<dim3(DI / 256, NC, BB), 256, 0, stream>>>(
            delta, ub, dbc, xr, lAlog, lDp, Sbuf, y16);

        gemm_out_part<<<192, 256, 0, stream>>>(y16, lw_outT, oprt);

        rmsnorm_fuse_kernel<<<MM, 256, 0, stream>>>(
            oprt, oprt + (size_t)MM * DM, lob, lnw, x, x16);
    }

    rmsnorm_kernel<<<MM, 256, 0, stream>>>(x, normf_w, nullptr, x16);

    // logits = xf @ emb^T  (256x128, 2 blocks/CU)
    gemm_logits<<<8 * (VPAD / 128), 512, 0, stream>>>(
        x16, emb16, out, MM, VV, DM, 8, VPAD / 128);
}